// Round 5
// baseline (5239.500 us; speedup 1.0000x reference)
//
#include <hip/hip_runtime.h>

// ---------------------------------------------------------------------------
// GRU autoencoder: B=128, T=512, E=H=256.  fp16 operands, fp32 state in regs.
//  prep   : fp32->fp16 weight repack into MFMA fragment order + bias folding
//  gemm_gi: gi_x = x @ Wih_e^T + (bih_e + bhh_e[rz])   [65536 x 768] fp16
//  enc    : persistent recurrence, 8 WGs x 16 rows x 8 waves (2/SIMD),
//           ALL weights in regs (AGPR-backed), gi staged via global_load_lds
//  dec0   : decoder step 0 (input=latents, state=0) - needs unfused Wih_d
//  dec    : persistent recurrence, rz-sum trick, ALL weights+biases in regs
// ---------------------------------------------------------------------------

typedef unsigned short u16;
typedef unsigned int   u32;

typedef _Float16 f16x8 __attribute__((ext_vector_type(8)));
typedef _Float16 f16x2 __attribute__((ext_vector_type(2)));
typedef float    f32x4 __attribute__((ext_vector_type(4)));

#define B_ 128
#define T_ 512
#define H_ 256
#define G3 768

// workspace layout (bytes)
#define GI_OFF     0ull                   // gi_x fp16 [65536][768]
#define WIH_OFF    100663296ull           // enc ih frag [48][8][64][8] fp16
#define WHH_OFF    101056512ull           // enc hh frag [48][8][64][8] fp16
#define WRZ_OFF    101449728ull           // dec rz-sum frag [32][8][64][8]
#define WIN_OFF    101711872ull           // dec in frag [16][8][64][8]
#define WHN_OFF    101842944ull           // dec hn frag [16][8][64][8]
#define BG_OFF     101974016ull           // gemm bias fp32 [768]
#define BHN_E_OFF  101977088ull           // enc bhh_n fp32 [256]
#define BDEC_OFF   101978112ull           // dec bias fp32 [1024] {brz,bin,bhn}
#define H1_OFF     101982208ull           // dec h1 fp32 [128][256]

// enc LDS layout (dynamic)
#define E_STG_L   0                       // 2 x 16 rows x 1600B = 51200
#define E_HL_L    51200                   // 2 x 1024 x 8B = 16384
#define ENC_LDS   67584

__device__ __forceinline__ float h2f(u16 u) {
    return (float)__builtin_bit_cast(_Float16, u);
}
__device__ __forceinline__ u16 f2h(float f) {
    _Float16 h = (_Float16)f;             // v_cvt_f16_f32, RNE
    return __builtin_bit_cast(u16, h);
}
__device__ __forceinline__ u32 pk2(float a, float b) {
    return __builtin_bit_cast(u32, __builtin_amdgcn_cvt_pkrtz(a, b));
}
__device__ __forceinline__ float sigf(float x) {
    return __builtin_amdgcn_rcpf(1.f + __builtin_amdgcn_exp2f(x * -1.4426950408889634f));
}
__device__ __forceinline__ float tanhf_(float x) {
    return 1.f - 2.f * __builtin_amdgcn_rcpf(1.f + __builtin_amdgcn_exp2f(x * 2.8853900817779268f));
}
__device__ __forceinline__ f16x8 ldfrag(const u16* base, int nt, int ks, int l) {
    return __builtin_bit_cast(f16x8, *(const uint4*)(base + ((size_t)((nt * 8 + ks) * 64 + l)) * 8));
}
__device__ __forceinline__ void gload_lds16(const void* g, void* l) {
    __builtin_amdgcn_global_load_lds(
        (const __attribute__((address_space(1))) unsigned int*)(g),
        (__attribute__((address_space(3))) unsigned int*)(l),
        16, 0, 0);
}
#define MFMA16(a, b, c) __builtin_amdgcn_mfma_f32_16x16x32_f16((a), (b), (c), 0, 0, 0)

// ---------------------------------------------------------------------------
// prep: pack weights into fragment order  W[nt*16 + lane%16][ks*32 + (lane/16)*8 + j]
// ---------------------------------------------------------------------------
__global__ __launch_bounds__(256) void prep_kernel(
    const float* __restrict__ Wih_e, const float* __restrict__ Whh_e,
    const float* __restrict__ bih_e, const float* __restrict__ bhh_e,
    const float* __restrict__ Wih_d, const float* __restrict__ Whh_d,
    const float* __restrict__ bih_d, const float* __restrict__ bhh_d,
    char* ws)
{
    int gid = blockIdx.x * 256 + threadIdx.x;
    const int NFRAG = 160 * 8 * 64;
    if (gid < NFRAG) {
        int lane = gid & 63;
        int ks = (gid >> 6) & 7;
        int a = gid >> 9;
        int lm = lane & 15, lg = lane >> 4;
        int k0 = ks * 32 + lg * 8;
        const float* s0; const float* s1 = nullptr; u16* dst; int nt;
        if (a < 48)       { nt = a;       s0 = Wih_e + (size_t)(nt*16+lm)*256 + k0;            dst = (u16*)(ws + WIH_OFF); }
        else if (a < 96)  { nt = a - 48;  s0 = Whh_e + (size_t)(nt*16+lm)*256 + k0;            dst = (u16*)(ws + WHH_OFF); }
        else if (a < 128) { nt = a - 96;  s0 = Wih_d + (size_t)(nt*16+lm)*256 + k0;
                            s1 = Whh_d + (size_t)(nt*16+lm)*256 + k0;                          dst = (u16*)(ws + WRZ_OFF); }
        else if (a < 144) { nt = a - 128; s0 = Wih_d + (size_t)(512+nt*16+lm)*256 + k0;        dst = (u16*)(ws + WIN_OFF); }
        else              { nt = a - 144; s0 = Whh_d + (size_t)(512+nt*16+lm)*256 + k0;        dst = (u16*)(ws + WHN_OFF); }
        u32 wd[4];
        #pragma unroll
        for (int p = 0; p < 4; ++p) {
            float v0 = s0[2*p]   + (s1 ? s1[2*p]   : 0.f);
            float v1 = s0[2*p+1] + (s1 ? s1[2*p+1] : 0.f);
            wd[p] = (u32)f2h(v0) | ((u32)f2h(v1) << 16);
        }
        uint4 o; o.x = wd[0]; o.y = wd[1]; o.z = wd[2]; o.w = wd[3];
        *(uint4*)(dst + ((size_t)((nt * 8 + ks) * 64 + lane)) * 8) = o;
    } else if (gid < NFRAG + 2048) {
        int bid = gid - NFRAG;
        if (bid < 768) {
            ((float*)(ws + BG_OFF))[bid] = bih_e[bid] + (bid < 512 ? bhh_e[bid] : 0.f);
        } else if (bid < 1024) {
            int j = bid - 768;  ((float*)(ws + BHN_E_OFF))[j] = bhh_e[512 + j];
        } else if (bid < 1536) {
            int j = bid - 1024; ((float*)(ws + BDEC_OFF))[j] = bih_d[j] + bhh_d[j];
        } else if (bid < 1792) {
            int j = bid - 1536; ((float*)(ws + BDEC_OFF))[512 + j] = bih_d[512 + j];
        } else {
            int j = bid - 1792; ((float*)(ws + BDEC_OFF))[768 + j] = bhh_d[512 + j];
        }
    }
}

// ---------------------------------------------------------------------------
// gemm_gi: gi_x[m][g] = sum_k x[m][k]*Wih_e[g][k] + bias[g], m = b*512+t
// ---------------------------------------------------------------------------
__global__ __launch_bounds__(256) void gemm_gi(const float* __restrict__ x, char* ws)
{
    extern __shared__ char smem[];
    ushort4* xl = (ushort4*)smem;  // [128 rows][64 8B-units], XOR-swizzled
    const u16* Wfrag = (const u16*)(ws + WIH_OFF);
    const float* bias = (const float*)(ws + BG_OFF);
    u16* gi = (u16*)(ws + GI_OFF);
    int tid = threadIdx.x;
    int m0 = blockIdx.x * 128;
    int n0 = blockIdx.y * 128;
    {   // stage x tile fp32->fp16 (full K=256)
        int row = tid >> 1, half = tid & 1;
        const float* src = x + (size_t)(m0 + row) * 256 + half * 128;
        #pragma unroll
        for (int q = 0; q < 32; ++q) {
            f32x4 v = *(const f32x4*)(src + q * 4);
            int vv = (row << 6) + (half * 32 + q);
            vv ^= ((row & 7) << 1);
            xl[vv] = make_ushort4(f2h(v.x), f2h(v.y), f2h(v.z), f2h(v.w));
        }
    }
    __syncthreads();
    int l = tid & 63, w = tid >> 6;
    int lm = l & 15, lg = l >> 4;
    int gh = w >> 1, mh = w & 1;
    const f32x4 Z4 = {0.f, 0.f, 0.f, 0.f};
    f32x4 acc[4][4];
    #pragma unroll
    for (int a = 0; a < 4; ++a)
        #pragma unroll
        for (int b = 0; b < 4; ++b) acc[a][b] = Z4;
    #pragma unroll
    for (int ks = 0; ks < 8; ++ks) {
        f16x8 xf[4], wf[4];
        #pragma unroll
        for (int mt = 0; mt < 4; ++mt) {
            int row = mh * 64 + mt * 16 + lm;
            int vv = (row << 6) + ((ks * 4 + lg) << 1);
            vv ^= ((row & 7) << 1);
            xf[mt] = __builtin_bit_cast(f16x8, *(const uint4*)&xl[vv]);
        }
        #pragma unroll
        for (int gt = 0; gt < 4; ++gt)
            wf[gt] = ldfrag(Wfrag, (n0 >> 4) + gh * 4 + gt, ks, l);
        #pragma unroll
        for (int gt = 0; gt < 4; ++gt)
            #pragma unroll
            for (int mt = 0; mt < 4; ++mt)
                acc[gt][mt] = MFMA16(wf[gt], xf[mt], acc[gt][mt]);
    }
    #pragma unroll
    for (int gt = 0; gt < 4; ++gt) {
        int g0 = n0 + (gh * 4 + gt) * 16 + lg * 4;
        f32x4 bv = *(const f32x4*)(bias + g0);
        #pragma unroll
        for (int mt = 0; mt < 4; ++mt) {
            int m = m0 + mh * 64 + mt * 16 + lm;
            f32x4 v = acc[gt][mt] + bv;
            *(ushort4*)(gi + (size_t)m * 768 + g0) =
                make_ushort4(f2h(v.x), f2h(v.y), f2h(v.z), f2h(v.w));
        }
    }
}

// ---------------------------------------------------------------------------
// encoder: 8 WGs x 16 rows, 8 waves (2/SIMD). Wave w owns h-cols [32w,32w+32).
// ALL weights (Wr/Wz/Wn [2][8], 192 regs, AGPR-backed) + bhn in registers.
// LDS: gi stage (dbuf, global_load_lds), h dbuf. 1 barrier/step.
// ---------------------------------------------------------------------------
__global__ __launch_bounds__(512, 2) void enc_kernel(char* ws, float* __restrict__ dout)
{
    extern __shared__ char smem[];
    char*    stg = smem + E_STG_L;                 // 2 x [16][1600]
    ushort4* hl  = (ushort4*)(smem + E_HL_L);      // 2 x 1024 units
    const u16* Wf = (const u16*)(ws + WHH_OFF);
    const u16* gi = (const u16*)(ws + GI_OFF);
    float* lat = dout + (size_t)B_ * T_ * H_;
    int tid = threadIdx.x;
    int l = tid & 63, w = tid >> 6;
    int lm = l & 15, lg = l >> 4, lg4 = lg * 4;
    int b0 = blockIdx.x * 16;

    #pragma unroll
    for (int q = 0; q < 2; ++q) hl[tid + q * 512] = make_ushort4(0, 0, 0, 0);  // hl[0]=0

    f16x8 Wr[2][8], Wz[2][8], Wn[2][8];
    #pragma unroll
    for (int i = 0; i < 2; ++i)
        #pragma unroll
        for (int ks = 0; ks < 8; ++ks) {
            Wr[i][ks] = ldfrag(Wf, 2 * w + i, ks, l);
            Wz[i][ks] = ldfrag(Wf, 16 + 2 * w + i, ks, l);
            Wn[i][ks] = ldfrag(Wf, 32 + 2 * w + i, ks, l);
        }
    f32x4 bnb[2];
    #pragma unroll
    for (int i = 0; i < 2; ++i)
        bnb[i] = *(const f32x4*)((const float*)(ws + BHN_E_OFF) + (2 * w + i) * 16 + lg4);

    // gi staging offsets (u16 units); 25 windows of 1024B per step
    u32 goff[4];
    #pragma unroll
    for (int q = 0; q < 4; ++q) {
        int s = w + q * 8; if (s > 24) s = 24;
        int u = s * 64 + l;
        int row = u / 100, c = u % 100; if (c > 95) c = 95;
        goff[q] = ((u32)(b0 + row) * T_) * G3 + (u32)c * 8;
    }
    {   // prologue: stage t=0 into buf 0
        #pragma unroll
        for (int q = 0; q < 4; ++q) {
            int s = w + q * 8;
            if (q < 3 || w == 0)
                gload_lds16(gi + goff[q], stg + s * 1024);
        }
    }
    __syncthreads();

    const f32x4 Z4 = {0.f, 0.f, 0.f, 0.f};
    f32x4 hreg[2] = {Z4, Z4};
    int cur = 0;

    for (int t = 0; t < 512; ++t) {
        int nxt = cur ^ 1;
        int tn = (t + 1) & 511;
        {   // prefetch t+1 (completion enforced by end-of-step barrier)
            char* sb = stg + nxt * 25600;
            #pragma unroll
            for (int q = 0; q < 4; ++q) {
                int s = w + q * 8;
                if (q < 3 || w == 0)
                    gload_lds16(gi + goff[q] + (u32)tn * G3, sb + s * 1024);
            }
        }
        const ushort4* hc = hl + cur * 1024;
        ushort4* hd = hl + nxt * 1024;
        const char* rb = stg + cur * 25600 + lm * 1600;

        f16x8 hb[8];                       // all h fragments up front
        #pragma unroll
        for (int ks = 0; ks < 8; ++ks) {
            int vv = (lm << 6) + ((ks * 4 + lg) << 1);
            vv ^= ((lm & 7) << 1);
            hb[ks] = __builtin_bit_cast(f16x8, *(const uint4*)&hc[vv]);
        }
        ushort4 gR[2], gZ[2], gN[2];
        #pragma unroll
        for (int i = 0; i < 2; ++i) {
            int j0 = (2 * w + i) * 16 + lg4;
            gR[i] = *(const ushort4*)(rb + j0 * 2);
            gZ[i] = *(const ushort4*)(rb + 512 + j0 * 2);
            gN[i] = *(const ushort4*)(rb + 1024 + j0 * 2);
        }
        #pragma unroll
        for (int i = 0; i < 2; ++i) {
            int j0 = (2 * w + i) * 16 + lg4;
            f32x4 aR = {h2f(gR[i].x), h2f(gR[i].y), h2f(gR[i].z), h2f(gR[i].w)};
            f32x4 aZ = {h2f(gZ[i].x), h2f(gZ[i].y), h2f(gZ[i].z), h2f(gZ[i].w)};
            f32x4 aN = Z4;
            __builtin_amdgcn_s_setprio(1);
            #pragma unroll
            for (int ks = 0; ks < 8; ++ks) {
                aR = MFMA16(Wr[i][ks], hb[ks], aR);
                aZ = MFMA16(Wz[i][ks], hb[ks], aZ);
                aN = MFMA16(Wn[i][ks], hb[ks], aN);
            }
            __builtin_amdgcn_s_setprio(0);
            float r0 = sigf(aR.x), z0 = sigf(aZ.x);
            float n0 = tanhf_(h2f(gN[i].x) + r0 * (aN.x + bnb[i].x));
            float h0 = n0 + z0 * (hreg[i].x - n0);
            float r1 = sigf(aR.y), z1 = sigf(aZ.y);
            float n1 = tanhf_(h2f(gN[i].y) + r1 * (aN.y + bnb[i].y));
            float h1 = n1 + z1 * (hreg[i].y - n1);
            float r2 = sigf(aR.z), z2 = sigf(aZ.z);
            float n2 = tanhf_(h2f(gN[i].z) + r2 * (aN.z + bnb[i].z));
            float h2 = n2 + z2 * (hreg[i].z - n2);
            float r3 = sigf(aR.w), z3 = sigf(aZ.w);
            float n3 = tanhf_(h2f(gN[i].w) + r3 * (aN.w + bnb[i].w));
            float h3 = n3 + z3 * (hreg[i].w - n3);
            f32x4 hv = {h0, h1, h2, h3};
            hreg[i] = hv;
            int vh = (lm << 6) + (j0 >> 2);
            vh ^= ((lm & 7) << 1);
            *(uint2*)&hd[vh] = make_uint2(pk2(h0, h1), pk2(h2, h3));
            if (t == 511) *(f32x4*)(lat + (size_t)(b0 + lm) * 256 + j0) = hv;
        }
        __syncthreads();
        cur = nxt;
    }
}

// ---------------------------------------------------------------------------
// decoder step 0: hx0 = cell(latents, 0); out[:,511,:] = hx0; ws.h1 = hx0
// ---------------------------------------------------------------------------
__global__ __launch_bounds__(256) void dec0_kernel(
    const float* __restrict__ Wih_d, const float* __restrict__ bih_d,
    const float* __restrict__ bhh_d, char* ws, float* __restrict__ dout)
{
    __shared__ float latl[256];
    int b = blockIdx.x, j = threadIdx.x;
    const float* latg = dout + (size_t)B_ * T_ * H_;
    latl[j] = latg[(size_t)b * 256 + j];
    __syncthreads();
    const float* wr = Wih_d + (size_t)j * 256;
    const float* wz = Wih_d + (size_t)(256 + j) * 256;
    const float* wn = Wih_d + (size_t)(512 + j) * 256;
    float sr = 0.f, sz = 0.f, sn = 0.f;
    #pragma unroll 4
    for (int k = 0; k < 256; ++k) {
        float h = latl[k];
        sr = fmaf(h, wr[k], sr); sz = fmaf(h, wz[k], sz); sn = fmaf(h, wn[k], sn);
    }
    float r = sigf(sr + bih_d[j] + bhh_d[j]);
    float z = sigf(sz + bih_d[256 + j] + bhh_d[256 + j]);
    float n = tanhf_(sn + bih_d[512 + j] + r * bhh_d[512 + j]);
    float h1v = (1.f - z) * n;
    ((float*)(ws + H1_OFF))[(size_t)b * 256 + j] = h1v;
    dout[((size_t)b * 512 + 511) * 256 + j] = h1v;
}

// ---------------------------------------------------------------------------
// decoder: steps 1..511. ALL weights (Wr/Wz/Wi/Wn [2][8], 256 regs) + all
// biases in registers; LDS holds only the double-buffered h (16KB static).
// ---------------------------------------------------------------------------
__global__ __launch_bounds__(512, 2) void dec_kernel(char* ws, float* __restrict__ dout)
{
    __shared__ ushort4 hl[2][1024];
    const u16* Wrzf = (const u16*)(ws + WRZ_OFF);
    const u16* Winf = (const u16*)(ws + WIN_OFF);
    const u16* Whnf = (const u16*)(ws + WHN_OFF);
    const float* bdec = (const float*)(ws + BDEC_OFF);
    const float* h1 = (const float*)(ws + H1_OFF);
    int tid = threadIdx.x;
    int l = tid & 63, w = tid >> 6;
    int lm = l & 15, lg = l >> 4, lg4 = lg * 4;
    int b0 = blockIdx.x * 16;

    #pragma unroll
    for (int q = 0; q < 2; ++q) {      // hl[0] <- fp16(h1)
        int u = tid + q * 512;
        int row = u >> 6, cu = u & 63;
        const float* s = h1 + (size_t)(b0 + row) * 256 + cu * 4;
        int vv = u ^ ((row & 7) << 1);
        hl[0][vv] = make_ushort4(f2h(s[0]), f2h(s[1]), f2h(s[2]), f2h(s[3]));
    }
    f16x8 Wr[2][8], Wz[2][8], Wi[2][8], Wn[2][8];
    #pragma unroll
    for (int i = 0; i < 2; ++i)
        #pragma unroll
        for (int ks = 0; ks < 8; ++ks) {
            Wr[i][ks] = ldfrag(Wrzf, 2 * w + i, ks, l);
            Wz[i][ks] = ldfrag(Wrzf, 16 + 2 * w + i, ks, l);
            Wi[i][ks] = ldfrag(Winf, 2 * w + i, ks, l);
            Wn[i][ks] = ldfrag(Whnf, 2 * w + i, ks, l);
        }
    f32x4 bR[2], bZ[2], bI[2], bN[2];
    #pragma unroll
    for (int i = 0; i < 2; ++i) {
        int jb = (2 * w + i) * 16 + lg4;
        bR[i] = *(const f32x4*)(bdec + jb);
        bZ[i] = *(const f32x4*)(bdec + 256 + jb);
        bI[i] = *(const f32x4*)(bdec + 512 + jb);
        bN[i] = *(const f32x4*)(bdec + 768 + jb);
    }
    const f32x4 Z4 = {0.f, 0.f, 0.f, 0.f};
    f32x4 hreg[2];
    #pragma unroll
    for (int i = 0; i < 2; ++i) {
        int j0 = (2 * w + i) * 16 + lg4;
        hreg[i] = *(const f32x4*)(h1 + (size_t)(b0 + lm) * 256 + j0);
    }
    __syncthreads();
    int cur = 0;

    for (int it = 1; it < 512; ++it) {
        int nxt = cur ^ 1;
        int trow = 511 - it;
        const ushort4* hc = hl[cur];
        ushort4* hd = hl[nxt];

        f16x8 hb[8];                       // all h fragments up front
        #pragma unroll
        for (int ks = 0; ks < 8; ++ks) {
            int vv = (lm << 6) + ((ks * 4 + lg) << 1);
            vv ^= ((lm & 7) << 1);
            hb[ks] = __builtin_bit_cast(f16x8, *(const uint4*)&hc[vv]);
        }
        #pragma unroll
        for (int i = 0; i < 2; ++i) {
            int jb = (2 * w + i) * 16 + lg4;
            f32x4 aR = bR[i], aZ = bZ[i], aI = bI[i], aN = Z4;
            __builtin_amdgcn_s_setprio(1);
            #pragma unroll
            for (int ks = 0; ks < 8; ++ks) {
                aR = MFMA16(Wr[i][ks], hb[ks], aR);
                aZ = MFMA16(Wz[i][ks], hb[ks], aZ);
                aI = MFMA16(Wi[i][ks], hb[ks], aI);
                aN = MFMA16(Wn[i][ks], hb[ks], aN);
            }
            __builtin_amdgcn_s_setprio(0);
            float r0 = sigf(aR.x), z0 = sigf(aZ.x);
            float n0 = tanhf_(aI.x + r0 * (aN.x + bN[i].x));
            float h0 = n0 + z0 * (hreg[i].x - n0);
            float r1 = sigf(aR.y), z1 = sigf(aZ.y);
            float n1 = tanhf_(aI.y + r1 * (aN.y + bN[i].y));
            float h1v = n1 + z1 * (hreg[i].y - n1);
            float r2 = sigf(aR.z), z2 = sigf(aZ.z);
            float n2 = tanhf_(aI.z + r2 * (aN.z + bN[i].z));
            float h2 = n2 + z2 * (hreg[i].z - n2);
            float r3 = sigf(aR.w), z3 = sigf(aZ.w);
            float n3 = tanhf_(aI.w + r3 * (aN.w + bN[i].w));
            float h3 = n3 + z3 * (hreg[i].w - n3);
            f32x4 hv = {h0, h1v, h2, h3};
            hreg[i] = hv;
            int vh = (lm << 6) + (jb >> 2);
            vh ^= ((lm & 7) << 1);
            *(uint2*)&hd[vh] = make_uint2(pk2(h0, h1v), pk2(h2, h3));
            *(f32x4*)(dout + ((size_t)(b0 + lm) * 512 + trow) * 256 + jb) = hv;
        }
        __syncthreads();
        cur = nxt;
    }
}

// ---------------------------------------------------------------------------
extern "C" void kernel_launch(void* const* d_in, const int* in_sizes, int n_in,
                              void* d_out, int out_size, void* d_ws, size_t ws_size,
                              hipStream_t stream)
{
    const float* x     = (const float*)d_in[0];
    const float* Wih_e = (const float*)d_in[1];
    const float* Whh_e = (const float*)d_in[2];
    const float* bih_e = (const float*)d_in[3];
    const float* bhh_e = (const float*)d_in[4];
    const float* Wih_d = (const float*)d_in[5];
    const float* Whh_d = (const float*)d_in[6];
    const float* bih_d = (const float*)d_in[7];
    const float* bhh_d = (const float*)d_in[8];
    char* ws = (char*)d_ws;
    float* out = (float*)d_out;

    (void)hipFuncSetAttribute((const void*)gemm_gi, hipFuncAttributeMaxDynamicSharedMemorySize, 65536);
    (void)hipFuncSetAttribute((const void*)enc_kernel, hipFuncAttributeMaxDynamicSharedMemorySize, ENC_LDS);

    prep_kernel<<<328, 256, 0, stream>>>(Wih_e, Whh_e, bih_e, bhh_e,
                                         Wih_d, Whh_d, bih_d, bhh_d, ws);
    gemm_gi<<<dim3(512, 6), 256, 65536, stream>>>(x, ws);
    enc_kernel<<<8, 512, ENC_LDS, stream>>>(ws, out);
    dec0_kernel<<<128, 256, 0, stream>>>(Wih_d, bih_d, bhh_d, ws, out);
    dec_kernel<<<8, 512, 0, stream>>>(ws, out);
}